// Round 1
// 835.604 us; speedup vs baseline: 1.4205x; 1.4205x over previous
//
#include <hip/hip_runtime.h>

#define B_ 16
#define T_ 2048
#define J_ 128
#define D_ 1024

// ws layout: float-indexed legacy region, then bf16 regions (byte offsets)
#define WS_UWB  0
#define WS_AGG2 2048
#define WSB_VH  73728UL                    // (w3*U)  hi  [b][j][d] bf16, 4 MB
#define WSB_VL  (WSB_VH  + 4194304UL)      // (w3*U)  lo
#define WSB_UTH (WSB_VL  + 4194304UL)      // U^T     hi  [b][d][j] bf16, 4 MB
#define WSB_UTL (WSB_UTH + 4194304UL)      // U^T     lo

// out layout (floats)
#define OFF_ATT1 0
#define OFF_ATT2 4194304UL
#define OFF_G    4227072UL

typedef float4 f4;
typedef unsigned short u16;
typedef unsigned int u32;
typedef __attribute__((ext_vector_type(8))) short short8;   // 8 bf16 = one MFMA A/B frag
typedef __attribute__((ext_vector_type(4))) float fx4;      // MFMA C/D frag

#define MFMA(A, B, C) __builtin_amdgcn_mfma_f32_16x16x32_bf16(A, B, C, 0, 0, 0)

__device__ __forceinline__ u16 f2bf(float f) {              // RNE float->bf16
    u32 u = __float_as_uint(f);
    u = (u + 0x7fffu + ((u >> 16) & 1u)) >> 16;
    return (u16)u;
}
__device__ __forceinline__ float bf2f(u16 h) { return __uint_as_float((u32)h << 16); }

__device__ __forceinline__ void split8(f4 a, f4 b, short8& h8, short8& l8) {
    float x[8] = {a.x, a.y, a.z, a.w, b.x, b.y, b.z, b.w};
#pragma unroll
    for (int i = 0; i < 8; ++i) {
        u16 h = f2bf(x[i]);
        u16 l = f2bf(x[i] - bf2f(h));
        h8[i] = (short)h;
        l8[i] = (short)l;
    }
}

// ---------------- K0: split (w3*U) -> Vh/Vl [b][j][d]; split U^T -> Uth/Utl [b][d][j]
__global__ __launch_bounds__(256) void k_prep(const float* __restrict__ U,
                                              const float* __restrict__ w,
                                              u16* __restrict__ Vh, u16* __restrict__ Vl,
                                              u16* __restrict__ Uth, u16* __restrict__ Utl) {
    const int b = blockIdx.y;
    const int j0 = blockIdx.x * 16;
    const int tid = threadIdx.x;
#pragma unroll
    for (int q = 0; q < 4; ++q) {
        int d = q * 256 + tid;
        float w3 = w[2 * D_ + d];
        u32 ph[8], pl[8];
#pragma unroll
        for (int jj = 0; jj < 16; ++jj) {
            size_t gi = ((size_t)(b * J_ + j0 + jj)) * D_ + d;
            float uval = U[gi];
            u16 uh = f2bf(uval);
            u16 ul = f2bf(uval - bf2f(uh));
            if (jj & 1) { ph[jj >> 1] |= (u32)uh << 16; pl[jj >> 1] |= (u32)ul << 16; }
            else        { ph[jj >> 1] = uh;             pl[jj >> 1] = ul; }
            float v = uval * w3;
            u16 vh = f2bf(v);
            Vh[gi] = vh;
            Vl[gi] = f2bf(v - bf2f(vh));
        }
        u16* tp = Uth + ((size_t)(b * D_ + d)) * J_ + j0;
        *(uint4*)tp       = make_uint4(ph[0], ph[1], ph[2], ph[3]);
        *(uint4*)(tp + 8) = make_uint4(ph[4], ph[5], ph[6], ph[7]);
        u16* lp = Utl + ((size_t)(b * D_ + d)) * J_ + j0;
        *(uint4*)lp       = make_uint4(pl[0], pl[1], pl[2], pl[3]);
        *(uint4*)(lp + 8) = make_uint4(pl[4], pl[5], pl[6], pl[7]);
    }
}

// ---------------- K1: uwb[b,j] = U[b,j,:].w2 + bias (unchanged) ----------------
__global__ __launch_bounds__(256) void k_uwb(const float* __restrict__ U,
                                             const float* __restrict__ w,
                                             const float* __restrict__ bias,
                                             float* __restrict__ ws) {
    int bj = blockIdx.x;
    const float* Urow = U + (size_t)bj * D_;
    const float* w2 = w + D_;
    float s = 0.f;
    for (int i = threadIdx.x; i < D_; i += 256) s = fmaf(Urow[i], w2[i], s);
#pragma unroll
    for (int off = 32; off > 0; off >>= 1) s += __shfl_down(s, off, 64);
    __shared__ float red[4];
    if ((threadIdx.x & 63) == 0) red[threadIdx.x >> 6] = s;
    __syncthreads();
    if (threadIdx.x == 0)
        ws[WS_UWB + bj] = red[0] + red[1] + red[2] + red[3] + bias[0];
}

// ---------------- K2: MFMA bf16x3 scores -> softmax -> att1,m -> MFMA agg1 -> G0..2
struct __align__(16) SMemM {
    union {
        struct { u16 Hh[64][72]; u16 Hl[64][72]; u16 Vh[128][72]; u16 Vl[128][72]; } g1; // 55296 B
        struct { float P[64][132]; u16 Uh[64][136]; u16 Ul[64][136]; } g2;               // 68608 B
    } u;
    float uwbs[J_];
    float hw[64];
};

__global__ __launch_bounds__(256) void k_main(const float* __restrict__ H,
                                              const float* __restrict__ w,
                                              const float* __restrict__ wsf,
                                              const u16* __restrict__ Vhg,
                                              const u16* __restrict__ Vlg,
                                              const u16* __restrict__ Uthg,
                                              const u16* __restrict__ Utlg,
                                              float* __restrict__ out) {
    __shared__ SMemM sm;
    const int tid = threadIdx.x;
    const int lane = tid & 63;
    const int wv = tid >> 6;        // wave 0..3 -> t-rows [wv*16, wv*16+16)
    const int lr = lane & 15;       // A row / B row / D col selector
    const int lg = lane >> 4;       // k-octet group
    const int b = blockIdx.y;
    const int t0 = blockIdx.x * 64;
    const float* Hb = H + ((size_t)b * T_ + t0) * D_;

    if (tid < J_) sm.uwbs[tid] = wsf[WS_UWB + b * J_ + tid];

    fx4 acc[8] = {};                 // S tile: 8 j-tiles x (4 rows/lane)
    float hwacc0 = 0.f, hwacc1 = 0.f;

    const int srow = tid >> 3;       // staging row 0..31
    const int sk8  = (tid & 7) * 8;  // staging k-octet

    // ---- GEMM1: S = H_tile(64xK) . (w3*U)^T(Kx128), K chunks of 64 ----
#pragma unroll 1
    for (int d0 = 0; d0 < D_; d0 += 64) {
        __syncthreads();
        f4 wa = *(const f4*)(w + d0 + sk8);          // w1 slice (for hw side-product)
        f4 wb = *(const f4*)(w + d0 + sk8 + 4);
        {
            const float* hp = Hb + (size_t)srow * D_ + d0 + sk8;
            f4 a = *(const f4*)hp; f4 c = *(const f4*)(hp + 4);
            hwacc0 = fmaf(a.x, wa.x, hwacc0); hwacc0 = fmaf(a.y, wa.y, hwacc0);
            hwacc0 = fmaf(a.z, wa.z, hwacc0); hwacc0 = fmaf(a.w, wa.w, hwacc0);
            hwacc0 = fmaf(c.x, wb.x, hwacc0); hwacc0 = fmaf(c.y, wb.y, hwacc0);
            hwacc0 = fmaf(c.z, wb.z, hwacc0); hwacc0 = fmaf(c.w, wb.w, hwacc0);
            short8 h8, l8; split8(a, c, h8, l8);
            *(short8*)&sm.u.g1.Hh[srow][sk8] = h8;
            *(short8*)&sm.u.g1.Hl[srow][sk8] = l8;
        }
        {
            const float* hp = Hb + (size_t)(srow + 32) * D_ + d0 + sk8;
            f4 a = *(const f4*)hp; f4 c = *(const f4*)(hp + 4);
            hwacc1 = fmaf(a.x, wa.x, hwacc1); hwacc1 = fmaf(a.y, wa.y, hwacc1);
            hwacc1 = fmaf(a.z, wa.z, hwacc1); hwacc1 = fmaf(a.w, wa.w, hwacc1);
            hwacc1 = fmaf(c.x, wb.x, hwacc1); hwacc1 = fmaf(c.y, wb.y, hwacc1);
            hwacc1 = fmaf(c.z, wb.z, hwacc1); hwacc1 = fmaf(c.w, wb.w, hwacc1);
            short8 h8, l8; split8(a, c, h8, l8);
            *(short8*)&sm.u.g1.Hh[srow + 32][sk8] = h8;
            *(short8*)&sm.u.g1.Hl[srow + 32][sk8] = l8;
        }
#pragma unroll
        for (int q = 0; q < 4; ++q) {                // V hi/lo, 128 rows x 64 k
            int slot = tid + q * 256;
            int row = slot >> 3;
            int k8 = (slot & 7) * 8;
            size_t gi = ((size_t)(b * J_ + row)) * D_ + d0 + k8;
            *(uint4*)&sm.u.g1.Vh[row][k8] = *(const uint4*)(Vhg + gi);
            *(uint4*)&sm.u.g1.Vl[row][k8] = *(const uint4*)(Vlg + gi);
        }
        __syncthreads();
#pragma unroll
        for (int ks = 0; ks < 2; ++ks) {
            int kk = ks * 32 + lg * 8;
            short8 ah = *(const short8*)&sm.u.g1.Hh[wv * 16 + lr][kk];
            short8 al = *(const short8*)&sm.u.g1.Hl[wv * 16 + lr][kk];
#pragma unroll
            for (int n = 0; n < 8; ++n) {
                short8 bh = *(const short8*)&sm.u.g1.Vh[n * 16 + lr][kk];
                short8 bl = *(const short8*)&sm.u.g1.Vl[n * 16 + lr][kk];
                acc[n] = MFMA(ah, bh, acc[n]);       // hi*hi
                acc[n] = MFMA(ah, bl, acc[n]);       // hi*lo
                acc[n] = MFMA(al, bh, acc[n]);       // lo*hi
            }
        }
    }

    // hw row-dots: reduce over the 8-lane k-groups, one writer per row
#pragma unroll
    for (int off = 1; off < 8; off <<= 1) {
        hwacc0 += __shfl_xor(hwacc0, off, 64);
        hwacc1 += __shfl_xor(hwacc1, off, 64);
    }
    if ((tid & 7) == 0) { sm.hw[srow] = hwacc0; sm.hw[srow + 32] = hwacc1; }
    __syncthreads();   // GEMM1 LDS dead beyond here; P may overwrite it

    // ---- softmax over j (hw & bias are const over j -> omitted), att1 + m' ----
    float* att1o = out + OFF_ATT1 + ((size_t)(b * T_ + t0 + wv * 16)) * J_;
    float* m_out = out + OFF_ATT2 + (size_t)b * T_ + t0 + wv * 16;
#pragma unroll
    for (int r = 0; r < 4; ++r) {
        float mx = -1e30f;
#pragma unroll
        for (int n = 0; n < 8; ++n) {
            float s = acc[n][r] + sm.uwbs[n * 16 + lr];
            acc[n][r] = s;
            mx = fmaxf(mx, s);
        }
#pragma unroll
        for (int off = 1; off < 16; off <<= 1) mx = fmaxf(mx, __shfl_xor(mx, off, 64));
        float sum = 0.f;
#pragma unroll
        for (int n = 0; n < 8; ++n) { float e = __expf(acc[n][r] - mx); acc[n][r] = e; sum += e; }
#pragma unroll
        for (int off = 1; off < 16; off <<= 1) sum += __shfl_xor(sum, off, 64);
        float inv = 1.f / sum;
        int row = lg * 4 + r;
#pragma unroll
        for (int n = 0; n < 8; ++n) {
            float p = acc[n][r] * inv;
            att1o[(size_t)row * J_ + n * 16 + lr] = p;
            sm.u.g2.P[wv * 16 + row][n * 16 + lr] = p;
        }
        if (lr == 0) m_out[row] = mx + sm.hw[wv * 16 + row];   // + hw; bias cancels in softmax_t
    }
    __syncthreads();

    // ---- GEMM2: agg1 = P(64x128) . U(128x1024) via U^T bf16 hi/lo ----
    short8 pha[4], pla[4];           // this wave's P rows as A-frags (k = j)
#pragma unroll
    for (int ks = 0; ks < 4; ++ks) {
        const float* pp = &sm.u.g2.P[wv * 16 + lr][ks * 32 + lg * 8];
        f4 p0 = *(const f4*)pp;
        f4 p1 = *(const f4*)(pp + 4);
        split8(p0, p1, pha[ks], pla[ks]);
    }

    float* Gb = out + OFF_G + ((size_t)(b * T_ + t0)) * 4096;
#pragma unroll 1
    for (int d0 = 0; d0 < D_; d0 += 64) {
        __syncthreads();
#pragma unroll
        for (int q = 0; q < 4; ++q) {                // stage U^T chunk: 64 d-rows x 128 j
            int slot = tid + q * 256;
            int row = slot >> 4;
            int j8 = (slot & 15) * 8;
            size_t gi = ((size_t)(b * D_ + d0 + row)) * J_ + j8;
            *(uint4*)&sm.u.g2.Uh[row][j8] = *(const uint4*)(Uthg + gi);
            *(uint4*)&sm.u.g2.Ul[row][j8] = *(const uint4*)(Utlg + gi);
        }
        __syncthreads();
        fx4 a2[4] = {};
#pragma unroll
        for (int ks = 0; ks < 4; ++ks) {
            int kk = ks * 32 + lg * 8;
#pragma unroll
            for (int n = 0; n < 4; ++n) {
                short8 bh = *(const short8*)&sm.u.g2.Uh[n * 16 + lr][kk];
                short8 bl = *(const short8*)&sm.u.g2.Ul[n * 16 + lr][kk];
                a2[n] = MFMA(pha[ks], bh, a2[n]);
                a2[n] = MFMA(pha[ks], bl, a2[n]);
                a2[n] = MFMA(pla[ks], bh, a2[n]);
            }
        }
#pragma unroll
        for (int n = 0; n < 4; ++n) {
#pragma unroll
            for (int r = 0; r < 4; ++r) {
                int row = wv * 16 + lg * 4 + r;
                int d = d0 + n * 16 + lr;
                float h = Hb[(size_t)row * D_ + d];
                float a = a2[n][r];
                float* g = Gb + (size_t)row * 4096 + d;
                g[0]    = h;
                g[1024] = a;
                g[2048] = h * a;
            }
        }
    }
}

// ---------------- K3: att2 = softmax_T(m) in-place (unchanged) ----------
__global__ __launch_bounds__(256) void k_att2(float* __restrict__ out) {
    int b = blockIdx.x, tid = threadIdx.x;
    float* mptr = out + OFF_ATT2 + (size_t)b * T_;
    float mv[8];
    float mx = -1e30f;
#pragma unroll
    for (int k = 0; k < 8; ++k) { mv[k] = mptr[tid + k * 256]; mx = fmaxf(mx, mv[k]); }
#pragma unroll
    for (int off = 1; off < 64; off <<= 1) mx = fmaxf(mx, __shfl_xor(mx, off, 64));
    __shared__ float redm[4], reds[4];
    if ((tid & 63) == 0) redm[tid >> 6] = mx;
    __syncthreads();
    float M = fmaxf(fmaxf(redm[0], redm[1]), fmaxf(redm[2], redm[3]));
    float s = 0.f;
#pragma unroll
    for (int k = 0; k < 8; ++k) { mv[k] = __expf(mv[k] - M); s += mv[k]; }
#pragma unroll
    for (int off = 1; off < 64; off <<= 1) s += __shfl_xor(s, off, 64);
    if ((tid & 63) == 0) reds[tid >> 6] = s;
    __syncthreads();
    float inv = 1.f / (reds[0] + reds[1] + reds[2] + reds[3]);
#pragma unroll
    for (int k = 0; k < 8; ++k) mptr[tid + k * 256] = mv[k] * inv;
}

// ---------------- K4: agg2[b,d] = sum_t att2[b,t] * H[b,t,d] (unchanged) ----
__global__ __launch_bounds__(256) void k_agg2(const float* __restrict__ H,
                                              const float* __restrict__ att2,
                                              float* __restrict__ ws) {
    int b = blockIdx.y;
    int d0 = blockIdx.x * 64;
    int c = threadIdx.x & 63;
    int tq = threadIdx.x >> 6;
    const float* Hb = H + (size_t)b * T_ * D_;
    const float* a2 = att2 + (size_t)b * T_;
    float acc = 0.f;
#pragma unroll 8
    for (int t = tq; t < T_; t += 4)
        acc = fmaf(a2[t], Hb[(size_t)t * D_ + d0 + c], acc);
    __shared__ float red[4][64];
    red[tq][c] = acc;
    __syncthreads();
    if (tq == 0)
        ws[WS_AGG2 + b * D_ + d0 + c] = red[0][c] + red[1][c] + red[2][c] + red[3][c];
}

// ---------------- K5: G chunk3 = H * agg2 (unchanged) -------------
__global__ __launch_bounds__(256) void k_chunk3(const float* __restrict__ H,
                                                const float* __restrict__ ws,
                                                float* __restrict__ out) {
    size_t id = (size_t)blockIdx.x * 256 + threadIdx.x;  // float4 index
    int d4 = (int)(id & 255);
    int t  = (int)((id >> 8) & 2047);
    int b  = (int)(id >> 19);
    f4 h = *(const f4*)(H + id * 4);
    f4 a = *(const f4*)(ws + WS_AGG2 + b * D_ + d4 * 4);
    f4 r = make_float4(h.x * a.x, h.y * a.y, h.z * a.z, h.w * a.w);
    *(f4*)(out + OFF_G + ((size_t)(b * T_ + t)) * 4096 + 3072 + d4 * 4) = r;
}

extern "C" void kernel_launch(void* const* d_in, const int* in_sizes, int n_in,
                              void* d_out, int out_size, void* d_ws, size_t ws_size,
                              hipStream_t stream) {
    const float* H    = (const float*)d_in[0];
    const float* U    = (const float*)d_in[1];
    const float* w    = (const float*)d_in[2];
    const float* bias = (const float*)d_in[3];
    float* out = (float*)d_out;
    float* ws  = (float*)d_ws;
    u16* wsVh  = (u16*)((char*)d_ws + WSB_VH);
    u16* wsVl  = (u16*)((char*)d_ws + WSB_VL);
    u16* wsUth = (u16*)((char*)d_ws + WSB_UTH);
    u16* wsUtl = (u16*)((char*)d_ws + WSB_UTL);

    k_prep  <<<dim3(J_ / 16, B_), dim3(256), 0, stream>>>(U, w, wsVh, wsVl, wsUth, wsUtl);
    k_uwb   <<<dim3(B_ * J_),     dim3(256), 0, stream>>>(U, w, bias, ws);
    k_main  <<<dim3(T_ / 64, B_), dim3(256), 0, stream>>>(H, w, ws, wsVh, wsVl, wsUth, wsUtl, out);
    k_att2  <<<dim3(B_),          dim3(256), 0, stream>>>(out);
    k_agg2  <<<dim3(D_ / 64, B_), dim3(256), 0, stream>>>(H, out + OFF_ATT2, ws);
    k_chunk3<<<dim3((B_ * T_ * (D_ / 4)) / 256), dim3(256), 0, stream>>>(H, ws, out);
}